// Round 5
// baseline (133.808 us; speedup 1.0000x reference)
//
#include <hip/hip_runtime.h>
#include <hip/hip_bf16.h>
#include <math.h>

// ---- problem constants ----
#define BATCH 16
#define CIN   128
#define COUT  128
#define SS    3136          // 56*56
#define XT_ROW 8192         // shorts per padded row: 64 pcol * 128 ci
#define XT_PER_B (58*XT_ROW)
#define NKB   18

typedef __attribute__((ext_vector_type(8))) __bf16 bf16x8;
typedef __attribute__((ext_vector_type(4))) float  floatx4;

static __device__ __forceinline__ unsigned short f2bf(float f) {
  union { float f; unsigned u; } v; v.f = f;
  unsigned r = v.u + 0x7fffu + ((v.u >> 16) & 1u);   // RNE
  return (unsigned short)(r >> 16);
}
static __device__ __forceinline__ float bf2f(unsigned short u) {
  union { unsigned u; float f; } v; v.u = ((unsigned)u) << 16; return v.f;
}

static __device__ __forceinline__ float waveReduceSum(float v) {
  #pragma unroll
  for (int off = 32; off > 0; off >>= 1) v += __shfl_xor(v, off, 64);
  return v;
}

static __device__ __forceinline__ void load_lds16(const void* g, void* l) {
  __builtin_amdgcn_global_load_lds(
      (const __attribute__((address_space(1))) void*)g,
      (__attribute__((address_space(3))) void*)l, 16, 0, 0);
}

// Raw barrier fenced on BOTH sides (llvm.amdgcn.s.barrier is IntrNoMem).
static __device__ __forceinline__ void barrier_fenced() {
  asm volatile("" ::: "memory");
  __builtin_amdgcn_s_barrier();
  asm volatile("" ::: "memory");
}

// LDS column-block swizzle: spreads banks across ci for transpose reads
static __device__ __forceinline__ int sswz(int ci) {
  return (ci ^ (ci >> 4)) & 15;
}

// K0: fused pad+transpose to NHWC bf16 + attention mask row + exp + per-row
// context partials. (FROZEN — unchanged since round 2, passing.)
__global__ __launch_bounds__(256, 4)
void k0_padT(const float* __restrict__ x, const float* __restrict__ w_mask,
             const float* __restrict__ b_mask,
             unsigned short* __restrict__ xT, float* __restrict__ rowsum,
             float* __restrict__ pctx) {
  int b = blockIdx.y, prow = blockIdx.x, t = threadIdx.x;
  int y = prow - 1;
  __shared__ __align__(16) unsigned short sx[128 * 64];
  __shared__ float swm[128];
  __shared__ float red[4 * 56];
  __shared__ float se[56];
  bool rowvalid = ((unsigned)y < 56u);

  if (!rowvalid) {                       // pad row: zero outputs directly
    unsigned short* dst = xT + (size_t)(b * 58 + prow) * XT_ROW;
    uint4 z4 = make_uint4(0u, 0u, 0u, 0u);
    #pragma unroll
    for (int q = 0; q < 4; q++)
      *reinterpret_cast<uint4*>(dst + (size_t)(t + 256 * q) * 8) = z4;
    if (t == 0) rowsum[b * 58 + prow] = 0.f;
    if (t < 128) pctx[(size_t)(b * 58 + prow) * 128 + t] = 0.f;
    return;
  }

  if (t < 128) swm[t] = w_mask[t];
  // load phase: 1792 float4 chunks, wave-coalesced (chunk = ci*14 + j)
  #pragma unroll
  for (int i = 0; i < 7; i++) {
    int c = t + 256 * i;
    int ci = c / 14, j = c - ci * 14;
    const float4 v = *reinterpret_cast<const float4*>(
        x + (size_t)(b * 128 + ci) * SS + y * 56 + j * 4);
    union { unsigned short s[4]; uint2 u; } pk;
    pk.s[0] = f2bf(v.x); pk.s[1] = f2bf(v.y);
    pk.s[2] = f2bf(v.z); pk.s[3] = f2bf(v.w);
    int blk = j ^ sswz(ci);
    *reinterpret_cast<uint2*>(&sx[ci * 64 + (blk << 2)]) = pk.u;
  }
  __syncthreads();

  // mask partials: thread (g, xx) dots 32 ci against w_mask
  if (t < 224) {
    int xx = t % 56, g = t / 56;
    float acc = 0.f;
    #pragma unroll
    for (int k = 0; k < 32; k++) {
      int ci = g * 32 + k;
      acc += bf2f(sx[ci * 64 + ((((xx >> 2) ^ sswz(ci)) << 2) | (xx & 3))]) * swm[ci];
    }
    red[g * 56 + xx] = acc;
  }
  __syncthreads();

  float e = 0.f;
  if (t < 56) {
    float m = red[t] + red[56 + t] + red[112 + t] + red[168 + t] + b_mask[0];
    e = expf(m);
    se[t] = e;
  }
  if (t < 64) {
    float s = waveReduceSum(e);
    if (t == 0) rowsum[b * 58 + prow] = s;   // 0 on pad rows
  }

  // NHWC write (only needs sx — overlap with exp work, before se-sync)
  {
    int pcol = t >> 2, cig = t & 3;
    int xx = pcol - 1;
    bool colv = ((unsigned)xx < 56u);
    unsigned short tmp[32];
    #pragma unroll
    for (int i = 0; i < 32; i++) {
      int ci = cig * 32 + i;
      tmp[i] = colv ? sx[ci * 64 + ((((xx >> 2) ^ sswz(ci)) << 2) | (xx & 3))]
                    : (unsigned short)0;
    }
    unsigned short* dst = xT + ((size_t)(b * 58 + prow) * 64 + pcol) * 128 + cig * 32;
    #pragma unroll
    for (int q = 0; q < 4; q++)
      *reinterpret_cast<uint4*>(dst + q * 8) = *reinterpret_cast<const uint4*>(tmp + q * 8);
  }
  __syncthreads();   // se ready

  // context partials: thread (c = t>>1, h = t&1) does 28 MACs, pair-combine
  {
    int c = t >> 1, h = t & 1;
    float acc = 0.f;
    #pragma unroll
    for (int j = 0; j < 28; j++) {
      int col = h * 28 + j;
      acc += bf2f(sx[c * 64 + ((((col >> 2) ^ sswz(c)) << 2) | (col & 3))]) * se[col];
    }
    acc += __shfl_xor(acc, 1, 64);
    if (h == 0) pctx[(size_t)(b * 58 + prow) * 128 + c] = acc;
  }
}

// K5M: merged MLP + weight generation (k4 folded in; one fewer launch).
// grid (co=128, bp=8), 256 threads: bh = t>>7 selects b = bp*2+bh, tt = t&127.
// Each block redundantly computes the 2-sample MLP (~59 KB L2 reads/block,
// 60 MB chip-wide ~ 1.7 µs, overlapped across 4 blocks/CU), then does the
// same wgen scatter as round 2-3's k5. pctx is now read-only (no aliasing).
__global__ void k5m(const float* __restrict__ rowsum, const float* __restrict__ pctx,
                    const float* __restrict__ w1, const float* __restrict__ b1,
                    const float* __restrict__ ln_g, const float* __restrict__ ln_b,
                    const float* __restrict__ w2, const float* __restrict__ b2,
                    const float* __restrict__ w_fc, const float* __restrict__ b_fc,
                    unsigned short* __restrict__ wd) {
  int co = blockIdx.x, bp = blockIdx.y, t = threadIdx.x;
  int bh = t >> 7, tt = t & 127;
  int b = bp * 2 + bh;
  __shared__ unsigned short sw[2][1152];
  __shared__ float sc[2][128], st[2][16], sn[2][16], sa[2][2], shz[2];

  // ctx reduction: thread handles channel tt of its sample
  float acc = 0.f;
  #pragma unroll
  for (int r = 0; r < 58; r++) acc += pctx[(size_t)(b * 58 + r) * 128 + tt];
  // rowsum total: waves 0 (b0) and 2 (b1) — wave-uniform predicate
  if ((t & 64) == 0) {
    float rv = (tt < 58) ? rowsum[b * 58 + tt] : 0.f;
    float s = waveReduceSum(rv);
    if (tt == 0) shz[bh] = 1.0f / s;
  }
  __syncthreads();
  sc[bh][tt] = acc * shz[bh];
  __syncthreads();
  // stage 1: t = ctx @ w1^T + b1 (16 threads per sample)
  if (tt < 16) {
    float s = b1[tt];
    #pragma unroll 8
    for (int c = 0; c < 128; c++) s += sc[bh][c] * w1[tt * 128 + c];
    st[bh][tt] = s;
  }
  __syncthreads();
  // LayerNorm + ReLU
  if (tt < 16) {
    float mu = 0.f, m2 = 0.f;
    #pragma unroll
    for (int r = 0; r < 16; r++) { float v = st[bh][r]; mu += v; m2 += v * v; }
    mu *= (1.f / 16.f); m2 *= (1.f / 16.f);
    float rstd = rsqrtf(m2 - mu * mu + 1e-5f);
    float v = (st[bh][tt] - mu) * rstd * ln_g[tt] + ln_b[tt];
    sn[bh][tt] = fmaxf(v, 0.f);
  }
  __syncthreads();
  // stage 2: only rows 2co, 2co+1 of w2 needed per sample
  if (tt < 2) {
    int mo = 2 * co + tt;
    float s = b2[mo];
    #pragma unroll
    for (int r = 0; r < 16; r++) s += sn[bh][r] * w2[mo * 16 + r];
    sa[bh][tt] = 1.f / (1.f + expf(-s));
  }
  __syncthreads();

  // wgen: thread `tt` owns a contiguous 36 B strip of w_fc/b_fc
  const float* wr = w_fc + co * 1152 + tt * 9;
  const float* br = b_fc + co * 1152 + tt * 9;
  float a = sa[bh][tt >> 6];
  int kq = tt & 63;
  int pos = (((kq >> 3) ^ (co & 7)) << 3) | (kq & 7);
  int kb0 = tt >> 6;
  #pragma unroll
  for (int khw = 0; khw < 9; khw++) {
    float v = a * wr[khw] + br[khw];
    sw[bh][(khw * 2 + kb0) * 64 + pos] = f2bf(v);
  }
  __syncthreads();
  // 2 rows x 144 uint4 chunks = 288 chunks, grid-stride over 256 threads
  for (int c = t; c < 288; c += 256) {
    int row = c / 144, q = c - row * 144;
    unsigned short* dst = wd + (size_t)((bp * 2 + row) * 128 + co) * 1152 + q * 8;
    *reinterpret_cast<uint4*>(dst) = *reinterpret_cast<const uint4*>(&sw[row][q * 8]);
  }
}

// K6: implicit-GEMM conv, 512 threads, tile 128co x 128s, with XCD-aware
// block swizzle (T1). Working set per block is xT[b] (950 KB) + wd[b]
// (294 KB); a linear grid sprays all 16 b's across every XCD (20 MB >> 4 MiB
// L2 -> all 258 MB of staging traffic L3-bound, schedule-independent --
// explaining round 3's pipeline null). Grouping b in {2k, 2k+1} on XCD k
// drops the per-XCD set to 2.5 MB < L2. 448 % 8 == 0 -> bijective remap.
__global__ __launch_bounds__(512, 4) void k6_conv(const unsigned short* __restrict__ xT,
                                                  const unsigned short* __restrict__ wd,
                                                  float* __restrict__ out) {
  __shared__ __align__(16) unsigned short As[2][8192];   // [dbuf][co128][kq64]
  __shared__ __align__(16) unsigned short Bs[2][8192];   // [dbuf][s128][kq64]
  int t = threadIdx.x;
  // XCD swizzle: HW assigns block id round-robin to XCDs (id % 8). Give XCD k
  // the 56 blocks of samples 2k (j<28) and 2k+1 (j>=28).
  int id = blockIdx.x;
  int xcd = id & 7, j = id >> 3;
  int b  = 2 * xcd + (j >= 28 ? 1 : 0);
  int y0 = (j >= 28 ? j - 28 : j) * 2;
  int wave = t >> 6, lane = t & 63, l15 = lane & 15, quad = lane >> 4;
  int x7 = lane & 7;
  const unsigned short* wp  = wd + (size_t)b * (128 * 1152);
  const unsigned short* xTb = xT + (size_t)b * XT_PER_B;

  // DMA chunk ids (16B units): this thread covers ch0, ch1 of 1024
  int ch0 = wave * 128 + lane, ch1 = ch0 + 64;
  int offA0 = (ch0 >> 3) * 1152 + (ch0 & 7) * 8;      // + kb*64 per step
  int offA1 = (ch1 >> 3) * 1152 + (ch1 & 7) * 8;
  int s0 = ch0 >> 3, s1 = ch1 >> 3;
  int c_ = lane & 7;
  int sr0 = s0 / 56, sc0 = s0 - sr0 * 56; if (sr0 >= 2) { sr0 = 0; sc0 = 0; }
  int sr1 = s1 / 56, sc1 = s1 - sr1 * 56; if (sr1 >= 2) { sr1 = 0; sc1 = 0; }
  int offB0 = (y0 + sr0) * XT_ROW + sc0 * 128 + (c_ ^ (s0 & 7)) * 8;
  int offB1 = (y0 + sr1) * XT_ROW + sc1 * 128 + (c_ ^ (s1 & 7)) * 8;

  int s_base = (wave & 3) * 32;
  int co_b   = (wave >> 2) * 64;

  floatx4 acc[4][2];
  floatx4 zero = {0.f, 0.f, 0.f, 0.f};
  #pragma unroll
  for (int i = 0; i < 4; i++)
    #pragma unroll
    for (int j2 = 0; j2 < 2; j2++) acc[i][j2] = zero;

  auto stage = [&](int buf, int kb) {
    int khw = kb >> 1;
    int kh = khw / 3;
    int kw = khw - kh * 3;
    int dB = kh * XT_ROW + kw * 128 + ((kb & 1) << 6);
    int dA = kb * 64;
    load_lds16(wp + offA0 + dA, &As[buf][wave * 1024]);
    load_lds16(wp + offA1 + dA, &As[buf][wave * 1024 + 512]);
    load_lds16(xTb + offB0 + dB, &Bs[buf][wave * 1024]);
    load_lds16(xTb + offB1 + dB, &Bs[buf][wave * 1024 + 512]);
  };

  stage(0, 0);                            // 4 loads in flight
  for (int kb = 0; kb < NKB; kb++) {
    int cur = kb & 1;
    if (kb + 1 < NKB) {
      stage(cur ^ 1, kb + 1);             // 8 in flight
      asm volatile("s_waitcnt vmcnt(4)" ::: "memory");   // batch kb landed
    } else {
      asm volatile("s_waitcnt vmcnt(0)" ::: "memory");   // last batch
    }
    barrier_fenced();                     // buf[cur] ready for ALL waves
    __builtin_amdgcn_s_setprio(1);
    #pragma unroll
    for (int kk = 0; kk < 2; kk++) {
      bf16x8 af[4], bfr[2];
      int pc = ((kk * 4 + quad) ^ x7) << 3;
      #pragma unroll
      for (int i = 0; i < 4; i++)
        af[i] = *reinterpret_cast<const bf16x8*>(&As[cur][(co_b + i * 16 + l15) * 64 + pc]);
      #pragma unroll
      for (int j2 = 0; j2 < 2; j2++)
        bfr[j2] = *reinterpret_cast<const bf16x8*>(&Bs[cur][(s_base + j2 * 16 + l15) * 64 + pc]);
      #pragma unroll
      for (int i = 0; i < 4; i++)
        #pragma unroll
        for (int j2 = 0; j2 < 2; j2++)
          acc[i][j2] = __builtin_amdgcn_mfma_f32_16x16x32_bf16(af[i], bfr[j2], acc[i][j2], 0, 0, 0);
    }
    __builtin_amdgcn_s_setprio(0);
    barrier_fenced();                     // all waves done reading buf[cur]
  }

  // epilogue: D col (l15) -> s, row (quad*4+r) -> co
  float* ob = out + (size_t)b * COUT * SS + y0 * 56;
  #pragma unroll
  for (int i = 0; i < 4; i++) {
    #pragma unroll
    for (int j2 = 0; j2 < 2; j2++) {
      int sl = s_base + j2 * 16 + l15;
      if (sl < 112) {
        int row = (sl >= 56) ? 1 : 0;
        int col = sl - row * 56;
        #pragma unroll
        for (int r = 0; r < 4; r++) {
          int co = co_b + i * 16 + quad * 4 + r;
          ob[(size_t)co * SS + row * 56 + col] = acc[i][j2][r];
        }
      }
    }
  }
}

extern "C" void kernel_launch(void* const* d_in, const int* in_sizes, int n_in,
                              void* d_out, int out_size, void* d_ws, size_t ws_size,
                              hipStream_t stream) {
  const float* x      = (const float*)d_in[0];
  const float* w_mask = (const float*)d_in[1];
  const float* b_mask = (const float*)d_in[2];
  const float* w1     = (const float*)d_in[3];
  const float* b1     = (const float*)d_in[4];
  const float* ln_g   = (const float*)d_in[5];
  const float* ln_b   = (const float*)d_in[6];
  const float* w2     = (const float*)d_in[7];
  const float* b2     = (const float*)d_in[8];
  const float* w_fc   = (const float*)d_in[9];
  const float* b_fc   = (const float*)d_in[10];
  float* out = (float*)d_out;

  char* ws = (char*)d_ws;
  unsigned short* xT  = (unsigned short*)(ws);               // 15,204,352 B
  unsigned short* wdw = (unsigned short*)(ws + 15204352);    //  4,718,592 B
  float* rowsum = (float*)(ws + 19922944);                   //      3,712 B
  float* pctx   = (float*)(ws + 19927040);                   //    475,136 B

  k0_padT<<<dim3(58, 16),  dim3(256), 0, stream>>>(x, w_mask, b_mask, xT, rowsum, pctx);
  k5m    <<<dim3(128, 8),  dim3(256), 0, stream>>>(rowsum, pctx, w1, b1, ln_g, ln_b,
                                                   w2, b2, w_fc, b_fc, wdw);
  k6_conv<<<dim3(448),     dim3(512), 0, stream>>>(xT, wdw, out);
}